// Round 11
// baseline (166.175 us; speedup 1.0000x reference)
//
#include <hip/hip_runtime.h>

#define DIM 1024
#define HEADS 16
#define HD 64
#define BATCH 2
#define SEQ 2048
#define ROWS (BATCH*SEQ)          // 4096
#define EPS 1e-6f

typedef float f32x4  __attribute__((ext_vector_type(4)));
typedef float f32x16 __attribute__((ext_vector_type(16)));
typedef short s16x4  __attribute__((ext_vector_type(4)));
typedef short s16x8  __attribute__((ext_vector_type(8)));

static __device__ __forceinline__ short f2bf(float f) {
    union { float f; unsigned u; } x; x.f = f;
    unsigned r = x.u + 0x7FFFu + ((x.u >> 16) & 1u);
    return (short)(r >> 16);
}
static __device__ __forceinline__ s16x8 pack8(float4 lo, float4 hi) {
    s16x8 r;
    r[0]=f2bf(lo.x); r[1]=f2bf(lo.y); r[2]=f2bf(lo.z); r[3]=f2bf(lo.w);
    r[4]=f2bf(hi.x); r[5]=f2bf(hi.y); r[6]=f2bf(hi.z); r[7]=f2bf(hi.w);
    return r;
}
static __device__ __forceinline__ unsigned cvtpk(float a, float b) {
    unsigned r;
    asm("v_cvt_pk_bf16_f32 %0, %1, %2" : "=v"(r) : "v"(a), "v"(b));
    return r;
}
static __device__ __forceinline__ void gld16(short* l, const short* g) {
    __builtin_amdgcn_global_load_lds(
        (const __attribute__((address_space(1))) void*)g,
        (__attribute__((address_space(3))) void*)l, 16, 0, 0);
}

#define MFMA32(A,B,C) __builtin_amdgcn_mfma_f32_32x32x16_bf16(A, B, C, 0, 0, 0)
#define MFMA16(A,B,C) __builtin_amdgcn_mfma_f32_16x16x32_bf16(A, B, C, 0, 0, 0)

struct PA { s16x8 a, b; };
// P (lane's 32 keys for its q-col) -> two bf16 A-fragments (T12; proven r2-r9)
static __device__ __forceinline__ PA packP(const f32x16& s) {
    PA r;
    unsigned A0 = cvtpk(s[0], s[1]),  A1 = cvtpk(s[2], s[3]);
    unsigned B0 = cvtpk(s[4], s[5]),  B1 = cvtpk(s[6], s[7]);
    asm volatile("v_permlane32_swap_b32 %0, %1" : "+v"(A0), "+v"(B0));
    asm volatile("v_permlane32_swap_b32 %0, %1" : "+v"(A1), "+v"(B1));
    union { s16x8 v; unsigned u[4]; } w;
    w.u[0]=A0; w.u[1]=A1; w.u[2]=B0; w.u[3]=B1;
    r.a = w.v;
    unsigned C0 = cvtpk(s[8], s[9]),   C1 = cvtpk(s[10], s[11]);
    unsigned D0 = cvtpk(s[12], s[13]), D1 = cvtpk(s[14], s[15]);
    asm volatile("v_permlane32_swap_b32 %0, %1" : "+v"(C0), "+v"(D0));
    asm volatile("v_permlane32_swap_b32 %0, %1" : "+v"(C1), "+v"(D1));
    union { s16x8 v; unsigned u[4]; } w2;
    w2.u[0]=C0; w2.u[1]=C1; w2.u[2]=D0; w2.u[3]=D1;
    r.b = w2.v;
    return r;
}
// pairwise trees (compile-time indices; identical shape to r9's inline trees)
static __device__ __forceinline__ float tree_max(const f32x16& s) {
    float t[8];
    #pragma unroll
    for (int i = 0; i < 8; i++) t[i] = fmaxf(s[i], s[i+8]);
    #pragma unroll
    for (int i = 0; i < 4; i++) t[i] = fmaxf(t[i], t[i+4]);
    return fmaxf(fmaxf(t[0], t[2]), fmaxf(t[1], t[3]));
}
static __device__ __forceinline__ float tree_sum(const f32x16& s) {
    float t[8];
    #pragma unroll
    for (int i = 0; i < 8; i++) t[i] = s[i] + s[i+8];
    #pragma unroll
    for (int i = 0; i < 4; i++) t[i] += t[i+4];
    return (t[0] + t[2]) + (t[1] + t[3]);
}

// ---------------------------------------------------------------------------
// fp32 -> bf16 conversion for x, W_qkv, W_proj (one pass, vectorized)
// ---------------------------------------------------------------------------
__global__ __launch_bounds__(256) void convert3(
    const float* __restrict__ x, const float* __restrict__ wq,
    const float* __restrict__ wp,
    short* __restrict__ xb, short* __restrict__ wqb, short* __restrict__ wpb)
{
    const int idx = blockIdx.x * 256 + threadIdx.x;   // one 8-elem chunk
    const int C1 = 4194304/8, C2 = 3145728/8;
    const float* src; short* dst; int off;
    if (idx < C1)            { src = x;  dst = xb;  off = idx; }
    else if (idx < C1 + C2)  { src = wq; dst = wqb; off = idx - C1; }
    else                     { src = wp; dst = wpb; off = idx - C1 - C2; }
    float4 a = ((const float4*)src)[off*2];
    float4 b = ((const float4*)src)[off*2 + 1];
    ((s16x8*)dst)[off] = pack8(a, b);
}

// ---------------------------------------------------------------------------
// bf16 GEMM, m97 structure: 128x128 tile, BK=64, global_load_lds staging.
// MODE 0: fused per-head LayerNorm on q/k, scatter bf16 q/k/v to [B,H,N,D]
// MODE 1: bias add, fp32 out
// ---------------------------------------------------------------------------
#define BKG 64

template<int MODE>
__global__ __launch_bounds__(256) void gemm_bf16(
    const short* __restrict__ A, const short* __restrict__ W,
    const float* __restrict__ bias,
    const float* __restrict__ qg, const float* __restrict__ qbeta,
    const float* __restrict__ kg, const float* __restrict__ kbeta,
    short* __restrict__ qb, short* __restrict__ kb, short* __restrict__ vb,
    float* __restrict__ out)
{
    alignas(16) __shared__ short As[128*BKG];
    alignas(16) __shared__ short Bs[128*BKG];
    const int tid  = threadIdx.x;
    const int lane = tid & 63, wave = tid >> 6;
    const int wr = wave >> 1, wc = wave & 1;
    const int c = lane & 15, g = lane >> 4;
    const int brow = blockIdx.y * 128, bcol = blockIdx.x * 128;

    const int srow = lane >> 3;
    const int scol = (lane & 7) * 8;
    const short* ag = A + (size_t)(brow + srow)*DIM + scol;
    const short* wg = W + (size_t)(bcol + srow)*DIM + scol;

    f32x4 acc[4][4] = {};

    for (int k0 = 0; k0 < DIM; k0 += BKG) {
        #pragma unroll
        for (int j = 0; j < 4; j++) {
            const int rg = (wave*4 + j) * 8;
            gld16(&As[rg*BKG], ag + (size_t)rg*DIM + k0);
            gld16(&Bs[rg*BKG], wg + (size_t)rg*DIM + k0);
        }
        __syncthreads();

        #pragma unroll
        for (int ks = 0; ks < 2; ks++) {
            s16x8 af[4], bf[4];
            #pragma unroll
            for (int m = 0; m < 4; m++)
                af[m] = *(const s16x8*)&As[(wr*64 + m*16 + c)*BKG + ks*32 + g*8];
            #pragma unroll
            for (int n = 0; n < 4; n++)
                bf[n] = *(const s16x8*)&Bs[(wc*64 + n*16 + c)*BKG + ks*32 + g*8];
            #pragma unroll
            for (int m = 0; m < 4; m++)
                #pragma unroll
                for (int n = 0; n < 4; n++)
                    acc[m][n] = MFMA16(af[m], bf[n], acc[m][n]);
        }
        __syncthreads();
    }

    if (MODE == 0) {
        const int colbase = bcol + wc*64;
        const int t = colbase >> 10;               // 0:q 1:k 2:v
        const int h = (colbase >> 6) & 15;
        short* dst = (t == 0) ? qb : (t == 1) ? kb : vb;
        float gam[4], bet[4];
        float scale = 1.0f;
        if (t < 2) {
            const float* G  = (t == 0) ? qg : kg;
            const float* Bt = (t == 0) ? qbeta : kbeta;
            #pragma unroll
            for (int n = 0; n < 4; n++) { gam[n] = G[n*16 + c]; bet[n] = Bt[n*16 + c]; }
            if (t == 0) scale = 0.125f * 1.44269504088896340736f;  // D^-0.5 * log2e
        }
        #pragma unroll
        for (int m = 0; m < 4; m++) {
            #pragma unroll
            for (int j = 0; j < 4; j++) {
                const int row = brow + wr*64 + m*16 + g*4 + j;
                const int bi = row >> 11, ni = row & (SEQ-1);
                const size_t rb = ((size_t)(bi*HEADS + h)*SEQ + ni)*HD;
                float v0 = acc[m][0][j], v1 = acc[m][1][j];
                float v2 = acc[m][2][j], v3 = acc[m][3][j];
                if (t < 2) {
                    float s = (v0 + v1) + (v2 + v3);
                    s += __shfl_xor(s, 1); s += __shfl_xor(s, 2);
                    s += __shfl_xor(s, 4); s += __shfl_xor(s, 8);
                    const float mu = s * 0.015625f;
                    v0 -= mu; v1 -= mu; v2 -= mu; v3 -= mu;
                    float vv = (v0*v0 + v1*v1) + (v2*v2 + v3*v3);
                    vv += __shfl_xor(vv, 1); vv += __shfl_xor(vv, 2);
                    vv += __shfl_xor(vv, 4); vv += __shfl_xor(vv, 8);
                    const float rstd = rsqrtf(vv * 0.015625f + EPS);
                    v0 = (v0*rstd*gam[0] + bet[0]) * scale;
                    v1 = (v1*rstd*gam[1] + bet[1]) * scale;
                    v2 = (v2*rstd*gam[2] + bet[2]) * scale;
                    v3 = (v3*rstd*gam[3] + bet[3]) * scale;
                }
                dst[rb + 0*16 + c] = f2bf(v0);
                dst[rb + 1*16 + c] = f2bf(v1);
                dst[rb + 2*16 + c] = f2bf(v2);
                dst[rb + 3*16 + c] = f2bf(v3);
            }
        }
    } else {
        #pragma unroll
        for (int n = 0; n < 4; n++) {
            const int col = bcol + wc*64 + n*16 + c;
            const float bv = bias[col];
            #pragma unroll
            for (int m = 0; m < 4; m++) {
                #pragma unroll
                for (int j = 0; j < 4; j++) {
                    const int row = brow + wr*64 + m*16 + g*4 + j;
                    out[(size_t)row*DIM + col] = acc[m][n][j] + bv;
                }
            }
        }
    }
}

// ---------------------------------------------------------------------------
// Repack K,V into MFMA-fragment order so attn loads are lane-coalesced:
//  KP[bh][tile32][ks(0..3)][lane][e] = K[bh][tile*32+(lane&31)][ks*16+8*(lane>>5)+e]
//  VP[bh][tile32][idx(0..3)][lane][e] = V[bh][tile*32+(idx>>1)*16+8*(lane>>5)+e][(idx&1)*32+(lane&31)]
// ---------------------------------------------------------------------------
__global__ __launch_bounds__(256) void repack_kv(
    const short* __restrict__ kin, const short* __restrict__ vin,
    short* __restrict__ KP, short* __restrict__ VP)
{
    constexpr int LT = 72;
    alignas(16) __shared__ short Kl[64*LT];
    alignas(16) __shared__ short Vl[64*LT];
    const int bh = blockIdx.x, n0 = blockIdx.y * 64;
    const int tid = threadIdx.x;
    const int r = tid >> 2, cq = (tid & 3) * 16;
    {
        const short* ksrc = kin + ((size_t)bh*SEQ + n0 + r)*HD + cq;
        const short* vsrc = vin + ((size_t)bh*SEQ + n0 + r)*HD + cq;
        *(s16x8*)&Kl[r*LT + cq]     = *(const s16x8*)ksrc;
        *(s16x8*)&Kl[r*LT + cq + 8] = *(const s16x8*)(ksrc + 8);
        *(s16x8*)&Vl[r*LT + cq]     = *(const s16x8*)vsrc;
        *(s16x8*)&Vl[r*LT + cq + 8] = *(const s16x8*)(vsrc + 8);
    }
    __syncthreads();
    const int tt = tid >> 7;              // tile 0/1
    const int r2 = tid & 127;
    const int sub = r2 >> 5, lp = r2 & 31;
    const size_t tbase = ((size_t)bh*64 + blockIdx.y*2 + tt)*2048 + sub*512;
    #pragma unroll
    for (int g2 = 0; g2 < 2; g2++) {
        const int lane = 2*lp + g2;
        s16x8 val = *(const s16x8*)&Kl[(tt*32 + (lane & 31))*LT + sub*16 + 8*(lane >> 5)];
        *(s16x8*)&KP[tbase + lane*8] = val;
    }
    #pragma unroll
    for (int g2 = 0; g2 < 2; g2++) {
        const int lane = 2*lp + g2;
        const int hi = lane >> 5, l31 = lane & 31;
        s16x8 val;
        #pragma unroll
        for (int e = 0; e < 8; e++)
            val[e] = Vl[(tt*32 + (sub >> 1)*16 + 8*hi + e)*LT + (sub & 1)*32 + l31];
        *(s16x8*)&VP[tbase + lane*8] = val;
    }
}

// ---------------------------------------------------------------------------
// Flash attention, q64-per-wave: each wave owns 64 q rows (two 32-row S/O
// pipelines A,B sharing the K/V fragments) x half the keys (2-way split-K).
// Proven r9 idioms only: shfl_xor reduces, exp2f, register pipeline, T12/T13.
// 2-way merge through LDS at the end.
// ---------------------------------------------------------------------------
__global__ __launch_bounds__(256) void attn_kernel(
    const short* __restrict__ qbuf, const short* __restrict__ KP,
    const short* __restrict__ VP, short* __restrict__ aout)
{
    alignas(16) __shared__ float OL[2][64][64];   // [qg][lane][16 quads]
    __shared__ float ML[2][4][64];                // [qg][{mA,lA,mB,lB}][lane]

    const int bh = blockIdx.x, qgrp = blockIdx.y;  // bh=x: XCD = bh%8 (L2 locality)
    const int tid = threadIdx.x, wave = tid >> 6, lane = tid & 63;
    const int qg = wave >> 1, half = wave & 1;
    const int l31 = lane & 31, hi = lane >> 5;
    const int q0 = qgrp*128 + qg*64;

    s16x8 qfA[4], qfB[4];
    {
        const short* qrowA = qbuf + ((size_t)bh*SEQ + q0 + l31)*HD + 8*hi;
        #pragma unroll
        for (int ks = 0; ks < 4; ks++) {
            qfA[ks] = *(const s16x8*)(qrowA + 16*ks);
            qfB[ks] = *(const s16x8*)(qrowA + 32*HD + 16*ks);
        }
    }

    const short* kp = KP + ((size_t)bh*64 + half*32)*2048 + lane*8;
    const short* vp = VP + ((size_t)bh*64 + half*32)*2048 + lane*8;

    // prologue: tile 0 of this wave's K-half
    s16x8 kc0 = *(const s16x8*)(kp);
    s16x8 kc1 = *(const s16x8*)(kp + 512);
    s16x8 kc2 = *(const s16x8*)(kp + 1024);
    s16x8 kc3 = *(const s16x8*)(kp + 1536);
    s16x8 vc0 = *(const s16x8*)(vp);
    s16x8 vc1 = *(const s16x8*)(vp + 512);
    s16x8 vc2 = *(const s16x8*)(vp + 1024);
    s16x8 vc3 = *(const s16x8*)(vp + 1536);

    f32x16 oA0 = {}, oA1 = {}, oB0 = {}, oB1 = {};
    float mA = -1e30f, mB = -1e30f, lA = 0.f, lB = 0.f;

    for (int it = 0; it < 32; it++) {
        // S^T = K*Q for both q-halves (independent MFMA chains)
        f32x16 sA = {}, sB = {};
        __builtin_amdgcn_s_setprio(1);
        sA = MFMA32(kc0, qfA[0], sA);  sB = MFMA32(kc0, qfB[0], sB);
        sA = MFMA32(kc1, qfA[1], sA);  sB = MFMA32(kc1, qfB[1], sB);
        sA = MFMA32(kc2, qfA[2], sA);  sB = MFMA32(kc2, qfB[2], sB);
        sA = MFMA32(kc3, qfA[3], sA);  sB = MFMA32(kc3, qfB[3], sB);
        __builtin_amdgcn_s_setprio(0);

        // reload kc for next tile NOW (covered by softmax + PV below)
        const int nt = ((it + 1) & 31) * 2048;
        kc0 = *(const s16x8*)(kp + nt);
        kc1 = *(const s16x8*)(kp + nt + 512);
        kc2 = *(const s16x8*)(kp + nt + 1024);
        kc3 = *(const s16x8*)(kp + nt + 1536);
        __builtin_amdgcn_sched_barrier(0);

        // softmax (shfl_xor cross-half reduces — r9-proven)
        float pmaxA = tree_max(sA);
        pmaxA = fmaxf(pmaxA, __shfl_xor(pmaxA, 32));
        float pmaxB = tree_max(sB);
        pmaxB = fmaxf(pmaxB, __shfl_xor(pmaxB, 32));

        if (!__all((pmaxA - mA <= 8.0f) && (pmaxB - mB <= 8.0f))) {  // T13
            float mnA = fmaxf(mA, pmaxA), mnB = fmaxf(mB, pmaxB);
            float cA = exp2f(mA - mnA), cB = exp2f(mB - mnB);
            #pragma unroll
            for (int i = 0; i < 16; i++) {
                oA0[i] *= cA; oA1[i] *= cA;
                oB0[i] *= cB; oB1[i] *= cB;
            }
            lA *= cA; lB *= cB;
            mA = mnA; mB = mnB;
        }
        #pragma unroll
        for (int i = 0; i < 16; i++) {
            sA[i] = exp2f(sA[i] - mA);
            sB[i] = exp2f(sB[i] - mB);
        }
        float rsA = tree_sum(sA);
        rsA += __shfl_xor(rsA, 32);
        lA += rsA;
        float rsB = tree_sum(sB);
        rsB += __shfl_xor(rsB, 32);
        lB += rsB;

        // P -> bf16 A-fragments (T12)
        PA paA = packP(sA);
        PA paB = packP(sB);

        // O^T += V^T * P (both q-halves share vc)
        __builtin_amdgcn_s_setprio(1);
        oA0 = MFMA32(vc0, paA.a, oA0);  oB0 = MFMA32(vc0, paB.a, oB0);
        oA1 = MFMA32(vc1, paA.a, oA1);  oB1 = MFMA32(vc1, paB.a, oB1);
        oA0 = MFMA32(vc2, paA.b, oA0);  oB0 = MFMA32(vc2, paB.b, oB0);
        oA1 = MFMA32(vc3, paA.b, oA1);  oB1 = MFMA32(vc3, paB.b, oB1);
        __builtin_amdgcn_s_setprio(0);

        // reload vc for next tile
        vc0 = *(const s16x8*)(vp + nt);
        vc1 = *(const s16x8*)(vp + nt + 512);
        vc2 = *(const s16x8*)(vp + nt + 1024);
        vc3 = *(const s16x8*)(vp + nt + 1536);
    }

    // ---- merge the two K-halves ----
    if (half == 1) {
        float* ob = &OL[qg][lane][0];
        #pragma unroll
        for (int i = 0; i < 16; i++) {
            const int slot = (i + (lane & 15)) & 15;
            f32x4 v;
            if (i < 4)       { const int t=i;    v[0]=oA0[4*t]; v[1]=oA0[4*t+1]; v[2]=oA0[4*t+2]; v[3]=oA0[4*t+3]; }
            else if (i < 8)  { const int t=i-4;  v[0]=oA1[4*t]; v[1]=oA1[4*t+1]; v[2]=oA1[4*t+2]; v[3]=oA1[4*t+3]; }
            else if (i < 12) { const int t=i-8;  v[0]=oB0[4*t]; v[1]=oB0[4*t+1]; v[2]=oB0[4*t+2]; v[3]=oB0[4*t+3]; }
            else             { const int t=i-12; v[0]=oB1[4*t]; v[1]=oB1[4*t+1]; v[2]=oB1[4*t+2]; v[3]=oB1[4*t+3]; }
            *(f32x4*)(ob + slot*4) = v;
        }
        ML[qg][0][lane] = mA; ML[qg][1][lane] = lA;
        ML[qg][2][lane] = mB; ML[qg][3][lane] = lB;
    }
    __syncthreads();
    if (half == 0) {
        const float mA1 = ML[qg][0][lane], lA1 = ML[qg][1][lane];
        const float mB1 = ML[qg][2][lane], lB1 = ML[qg][3][lane];
        const float msA = fmaxf(mA, mA1), msB = fmaxf(mB, mB1);
        const float cA0 = exp2f(mA - msA), cA1 = exp2f(mA1 - msA);
        const float cB0 = exp2f(mB - msB), cB1 = exp2f(mB1 - msB);
        const float invA = 1.0f / (lA*cA0 + lA1*cA1);
        const float invB = 1.0f / (lB*cB0 + lB1*cB1);
        const int b = bh >> 4, h = bh & 15;
        short* dstA = aout + ((size_t)(b*SEQ + q0 + l31))*DIM + h*HD;
        short* dstB = dstA + (size_t)32*DIM;
        const float* ob = &OL[qg][lane][0];
        #pragma unroll
        for (int i = 0; i < 16; i++) {
            const int slot = (i + (lane & 15)) & 15;
            f32x4 p = *(const f32x4*)(ob + slot*4);
            s16x4 st;
            if (i < 4) {
                const int t = i;
                #pragma unroll
                for (int j = 0; j < 4; j++) st[j] = f2bf((oA0[4*t+j]*cA0 + p[j]*cA1) * invA);
                *(s16x4*)(dstA + 8*t + 4*hi) = st;
            } else if (i < 8) {
                const int t = i - 4;
                #pragma unroll
                for (int j = 0; j < 4; j++) st[j] = f2bf((oA1[4*t+j]*cA0 + p[j]*cA1) * invA);
                *(s16x4*)(dstA + 32 + 8*t + 4*hi) = st;
            } else if (i < 12) {
                const int t = i - 8;
                #pragma unroll
                for (int j = 0; j < 4; j++) st[j] = f2bf((oB0[4*t+j]*cB0 + p[j]*cB1) * invB);
                *(s16x4*)(dstB + 8*t + 4*hi) = st;
            } else {
                const int t = i - 12;
                #pragma unroll
                for (int j = 0; j < 4; j++) st[j] = f2bf((oB1[4*t+j]*cB0 + p[j]*cB1) * invB);
                *(s16x4*)(dstB + 32 + 8*t + 4*hi) = st;
            }
        }
    }
}

// ---------------------------------------------------------------------------
extern "C" void kernel_launch(void* const* d_in, const int* in_sizes, int n_in,
                              void* d_out, int out_size, void* d_ws, size_t ws_size,
                              hipStream_t stream)
{
    const float* x     = (const float*)d_in[0];
    const float* Wqkv  = (const float*)d_in[1];
    const float* qg    = (const float*)d_in[2];
    const float* qbeta = (const float*)d_in[3];
    const float* kg    = (const float*)d_in[4];
    const float* kbeta = (const float*)d_in[5];
    const float* Wproj = (const float*)d_in[6];
    const float* bproj = (const float*)d_in[7];
    float* out = (float*)d_out;

    char* ws = (char*)d_ws;
    const size_t MB = 1024*1024;
    short* xb     = (short*)(ws);              // 8 MB; dead after gemm<0>
    short* KP     = (short*)(ws);              // reuses xb slot (written by repack)
    short* wqkvb  = (short*)(ws + 8*MB);       // 6 MB
    short* wprojb = (short*)(ws + 14*MB);      // 2 MB (live until gemm<1>)
    short* q      = (short*)(ws + 16*MB);      // 8 MB
    short* k      = (short*)(ws + 24*MB);      // 8 MB; dead after repack
    short* aout   = (short*)(ws + 24*MB);      // reuses k slot (written by attn)
    short* vrow   = (short*)(ws + 32*MB);      // 8 MB; dead after repack
    short* VP     = (short*)(ws + 40*MB);      // 8 MB

    // 1. fp32 -> bf16 conversions
    convert3<<<dim3(4096), 256, 0, stream>>>(x, Wqkv, Wproj, xb, wqkvb, wprojb);

    // 2. QKV GEMM + fused q/k LayerNorm, scatter
    gemm_bf16<0><<<dim3(3*DIM/128, ROWS/128), 256, 0, stream>>>(
        xb, wqkvb, nullptr, qg, qbeta, kg, kbeta, q, k, vrow, nullptr);

    // 3. Repack K,V into fragment order
    repack_kv<<<dim3(BATCH*HEADS, SEQ/64), 256, 0, stream>>>(k, vrow, KP, VP);

    // 4. Flash attention (q64/wave, 2-way split-K, pipelined, bf16 out)
    attn_kernel<<<dim3(BATCH*HEADS, SEQ/128), 256, 0, stream>>>(q, KP, VP, aout);

    // 5. Projection GEMM + bias -> fp32 d_out
    gemm_bf16<1><<<dim3(DIM/128, ROWS/128), 256, 0, stream>>>(
        aout, wprojb, bproj, nullptr, nullptr, nullptr, nullptr,
        nullptr, nullptr, nullptr, out);
}

// Round 12
// 148.137 us; speedup vs baseline: 1.1218x; 1.1218x over previous
//
#include <hip/hip_runtime.h>

#define DIM 1024
#define HEADS 16
#define HD 64
#define BATCH 2
#define SEQ 2048
#define ROWS (BATCH*SEQ)          // 4096
#define EPS 1e-6f

typedef float f32x4  __attribute__((ext_vector_type(4)));
typedef float f32x16 __attribute__((ext_vector_type(16)));
typedef short s16x4  __attribute__((ext_vector_type(4)));
typedef short s16x8  __attribute__((ext_vector_type(8)));

static __device__ __forceinline__ short f2bf(float f) {
    union { float f; unsigned u; } x; x.f = f;
    unsigned r = x.u + 0x7FFFu + ((x.u >> 16) & 1u);
    return (short)(r >> 16);
}
static __device__ __forceinline__ s16x8 pack8(float4 lo, float4 hi) {
    s16x8 r;
    r[0]=f2bf(lo.x); r[1]=f2bf(lo.y); r[2]=f2bf(lo.z); r[3]=f2bf(lo.w);
    r[4]=f2bf(hi.x); r[5]=f2bf(hi.y); r[6]=f2bf(hi.z); r[7]=f2bf(hi.w);
    return r;
}
static __device__ __forceinline__ unsigned cvtpk(float a, float b) {
    unsigned r;
    asm("v_cvt_pk_bf16_f32 %0, %1, %2" : "=v"(r) : "v"(a), "v"(b));
    return r;
}
static __device__ __forceinline__ void gld16(short* l, const short* g) {
    __builtin_amdgcn_global_load_lds(
        (const __attribute__((address_space(1))) void*)g,
        (__attribute__((address_space(3))) void*)l, 16, 0, 0);
}

#define MFMA32(A,B,C) __builtin_amdgcn_mfma_f32_32x32x16_bf16(A, B, C, 0, 0, 0)
#define MFMA16(A,B,C) __builtin_amdgcn_mfma_f32_16x16x32_bf16(A, B, C, 0, 0, 0)

struct PA { s16x8 a, b; };
// P (lane's 32 keys for its q-col) -> two bf16 A-fragments (T12; proven r2-r11)
static __device__ __forceinline__ PA packP(const f32x16& s) {
    PA r;
    unsigned A0 = cvtpk(s[0], s[1]),  A1 = cvtpk(s[2], s[3]);
    unsigned B0 = cvtpk(s[4], s[5]),  B1 = cvtpk(s[6], s[7]);
    asm volatile("v_permlane32_swap_b32 %0, %1" : "+v"(A0), "+v"(B0));
    asm volatile("v_permlane32_swap_b32 %0, %1" : "+v"(A1), "+v"(B1));
    union { s16x8 v; unsigned u[4]; } w;
    w.u[0]=A0; w.u[1]=A1; w.u[2]=B0; w.u[3]=B1;
    r.a = w.v;
    unsigned C0 = cvtpk(s[8], s[9]),   C1 = cvtpk(s[10], s[11]);
    unsigned D0 = cvtpk(s[12], s[13]), D1 = cvtpk(s[14], s[15]);
    asm volatile("v_permlane32_swap_b32 %0, %1" : "+v"(C0), "+v"(D0));
    asm volatile("v_permlane32_swap_b32 %0, %1" : "+v"(C1), "+v"(D1));
    union { s16x8 v; unsigned u[4]; } w2;
    w2.u[0]=C0; w2.u[1]=C1; w2.u[2]=D0; w2.u[3]=D1;
    r.b = w2.v;
    return r;
}
// pairwise trees (compile-time indices; proven r11)
static __device__ __forceinline__ float tree_max(const f32x16& s) {
    float t[8];
    #pragma unroll
    for (int i = 0; i < 8; i++) t[i] = fmaxf(s[i], s[i+8]);
    #pragma unroll
    for (int i = 0; i < 4; i++) t[i] = fmaxf(t[i], t[i+4]);
    return fmaxf(fmaxf(t[0], t[2]), fmaxf(t[1], t[3]));
}
static __device__ __forceinline__ float tree_sum(const f32x16& s) {
    float t[8];
    #pragma unroll
    for (int i = 0; i < 8; i++) t[i] = s[i] + s[i+8];
    #pragma unroll
    for (int i = 0; i < 4; i++) t[i] += t[i+4];
    return (t[0] + t[2]) + (t[1] + t[3]);
}

// ---------------------------------------------------------------------------
// fp32 -> bf16 conversion for x, W_qkv, W_proj (one pass, vectorized)
// ---------------------------------------------------------------------------
__global__ __launch_bounds__(256) void convert3(
    const float* __restrict__ x, const float* __restrict__ wq,
    const float* __restrict__ wp,
    short* __restrict__ xb, short* __restrict__ wqb, short* __restrict__ wpb)
{
    const int idx = blockIdx.x * 256 + threadIdx.x;   // one 8-elem chunk
    const int C1 = 4194304/8, C2 = 3145728/8;
    const float* src; short* dst; int off;
    if (idx < C1)            { src = x;  dst = xb;  off = idx; }
    else if (idx < C1 + C2)  { src = wq; dst = wqb; off = idx - C1; }
    else                     { src = wp; dst = wpb; off = idx - C1 - C2; }
    float4 a = ((const float4*)src)[off*2];
    float4 b = ((const float4*)src)[off*2 + 1];
    ((s16x8*)dst)[off] = pack8(a, b);
}

// ---------------------------------------------------------------------------
// bf16 GEMM, m97 structure: 128x128 tile, BK=64, global_load_lds staging.
// MODE 0: fused per-head LayerNorm on q/k, scatter bf16 q/k/v to [B,H,N,D]
// MODE 1: bias add, fp32 out
// ---------------------------------------------------------------------------
#define BKG 64

template<int MODE>
__global__ __launch_bounds__(256) void gemm_bf16(
    const short* __restrict__ A, const short* __restrict__ W,
    const float* __restrict__ bias,
    const float* __restrict__ qg, const float* __restrict__ qbeta,
    const float* __restrict__ kg, const float* __restrict__ kbeta,
    short* __restrict__ qb, short* __restrict__ kb, short* __restrict__ vb,
    float* __restrict__ out)
{
    alignas(16) __shared__ short As[128*BKG];
    alignas(16) __shared__ short Bs[128*BKG];
    const int tid  = threadIdx.x;
    const int lane = tid & 63, wave = tid >> 6;
    const int wr = wave >> 1, wc = wave & 1;
    const int c = lane & 15, g = lane >> 4;
    const int brow = blockIdx.y * 128, bcol = blockIdx.x * 128;

    const int srow = lane >> 3;
    const int scol = (lane & 7) * 8;
    const short* ag = A + (size_t)(brow + srow)*DIM + scol;
    const short* wg = W + (size_t)(bcol + srow)*DIM + scol;

    f32x4 acc[4][4] = {};

    for (int k0 = 0; k0 < DIM; k0 += BKG) {
        #pragma unroll
        for (int j = 0; j < 4; j++) {
            const int rg = (wave*4 + j) * 8;
            gld16(&As[rg*BKG], ag + (size_t)rg*DIM + k0);
            gld16(&Bs[rg*BKG], wg + (size_t)rg*DIM + k0);
        }
        __syncthreads();

        #pragma unroll
        for (int ks = 0; ks < 2; ks++) {
            s16x8 af[4], bf[4];
            #pragma unroll
            for (int m = 0; m < 4; m++)
                af[m] = *(const s16x8*)&As[(wr*64 + m*16 + c)*BKG + ks*32 + g*8];
            #pragma unroll
            for (int n = 0; n < 4; n++)
                bf[n] = *(const s16x8*)&Bs[(wc*64 + n*16 + c)*BKG + ks*32 + g*8];
            #pragma unroll
            for (int m = 0; m < 4; m++)
                #pragma unroll
                for (int n = 0; n < 4; n++)
                    acc[m][n] = MFMA16(af[m], bf[n], acc[m][n]);
        }
        __syncthreads();
    }

    if (MODE == 0) {
        const int colbase = bcol + wc*64;
        const int t = colbase >> 10;               // 0:q 1:k 2:v
        const int h = (colbase >> 6) & 15;
        short* dst = (t == 0) ? qb : (t == 1) ? kb : vb;
        float gam[4], bet[4];
        float scale = 1.0f;
        if (t < 2) {
            const float* G  = (t == 0) ? qg : kg;
            const float* Bt = (t == 0) ? qbeta : kbeta;
            #pragma unroll
            for (int n = 0; n < 4; n++) { gam[n] = G[n*16 + c]; bet[n] = Bt[n*16 + c]; }
            if (t == 0) scale = 0.125f * 1.44269504088896340736f;  // D^-0.5 * log2e
        }
        #pragma unroll
        for (int m = 0; m < 4; m++) {
            #pragma unroll
            for (int j = 0; j < 4; j++) {
                const int row = brow + wr*64 + m*16 + g*4 + j;
                const int bi = row >> 11, ni = row & (SEQ-1);
                const size_t rb = ((size_t)(bi*HEADS + h)*SEQ + ni)*HD;
                float v0 = acc[m][0][j], v1 = acc[m][1][j];
                float v2 = acc[m][2][j], v3 = acc[m][3][j];
                if (t < 2) {
                    float s = (v0 + v1) + (v2 + v3);
                    s += __shfl_xor(s, 1); s += __shfl_xor(s, 2);
                    s += __shfl_xor(s, 4); s += __shfl_xor(s, 8);
                    const float mu = s * 0.015625f;
                    v0 -= mu; v1 -= mu; v2 -= mu; v3 -= mu;
                    float vv = (v0*v0 + v1*v1) + (v2*v2 + v3*v3);
                    vv += __shfl_xor(vv, 1); vv += __shfl_xor(vv, 2);
                    vv += __shfl_xor(vv, 4); vv += __shfl_xor(vv, 8);
                    const float rstd = rsqrtf(vv * 0.015625f + EPS);
                    v0 = (v0*rstd*gam[0] + bet[0]) * scale;
                    v1 = (v1*rstd*gam[1] + bet[1]) * scale;
                    v2 = (v2*rstd*gam[2] + bet[2]) * scale;
                    v3 = (v3*rstd*gam[3] + bet[3]) * scale;
                }
                dst[rb + 0*16 + c] = f2bf(v0);
                dst[rb + 1*16 + c] = f2bf(v1);
                dst[rb + 2*16 + c] = f2bf(v2);
                dst[rb + 3*16 + c] = f2bf(v3);
            }
        }
    } else {
        #pragma unroll
        for (int n = 0; n < 4; n++) {
            const int col = bcol + wc*64 + n*16 + c;
            const float bv = bias[col];
            #pragma unroll
            for (int m = 0; m < 4; m++) {
                #pragma unroll
                for (int j = 0; j < 4; j++) {
                    const int row = brow + wr*64 + m*16 + g*4 + j;
                    out[(size_t)row*DIM + col] = acc[m][n][j] + bv;
                }
            }
        }
    }
}

// ---------------------------------------------------------------------------
// Repack K,V into MFMA-fragment order so attn loads are lane-coalesced:
//  KP[bh][tile32][ks(0..3)][lane][e] = K[bh][tile*32+(lane&31)][ks*16+8*(lane>>5)+e]
//  VP[bh][tile32][idx(0..3)][lane][e] = V[bh][tile*32+(idx>>1)*16+8*(lane>>5)+e][(idx&1)*32+(lane&31)]
// ---------------------------------------------------------------------------
__global__ __launch_bounds__(256) void repack_kv(
    const short* __restrict__ kin, const short* __restrict__ vin,
    short* __restrict__ KP, short* __restrict__ VP)
{
    constexpr int LT = 72;
    alignas(16) __shared__ short Kl[64*LT];
    alignas(16) __shared__ short Vl[64*LT];
    const int bh = blockIdx.x, n0 = blockIdx.y * 64;
    const int tid = threadIdx.x;
    const int r = tid >> 2, cq = (tid & 3) * 16;
    {
        const short* ksrc = kin + ((size_t)bh*SEQ + n0 + r)*HD + cq;
        const short* vsrc = vin + ((size_t)bh*SEQ + n0 + r)*HD + cq;
        *(s16x8*)&Kl[r*LT + cq]     = *(const s16x8*)ksrc;
        *(s16x8*)&Kl[r*LT + cq + 8] = *(const s16x8*)(ksrc + 8);
        *(s16x8*)&Vl[r*LT + cq]     = *(const s16x8*)vsrc;
        *(s16x8*)&Vl[r*LT + cq + 8] = *(const s16x8*)(vsrc + 8);
    }
    __syncthreads();
    const int tt = tid >> 7;              // tile 0/1
    const int r2 = tid & 127;
    const int sub = r2 >> 5, lp = r2 & 31;
    const size_t tbase = ((size_t)bh*64 + blockIdx.y*2 + tt)*2048 + sub*512;
    #pragma unroll
    for (int g2 = 0; g2 < 2; g2++) {
        const int lane = 2*lp + g2;
        s16x8 val = *(const s16x8*)&Kl[(tt*32 + (lane & 31))*LT + sub*16 + 8*(lane >> 5)];
        *(s16x8*)&KP[tbase + lane*8] = val;
    }
    #pragma unroll
    for (int g2 = 0; g2 < 2; g2++) {
        const int lane = 2*lp + g2;
        const int hi = lane >> 5, l31 = lane & 31;
        s16x8 val;
        #pragma unroll
        for (int e = 0; e < 8; e++)
            val[e] = Vl[(tt*32 + (sub >> 1)*16 + 8*hi + e)*LT + (sub & 1)*32 + l31];
        *(s16x8*)&VP[tbase + lane*8] = val;
    }
}

// ---------------------------------------------------------------------------
// Flash attention: r9 structure (q32/wave, 2-way split-K, shfl_xor reduces,
// exp2f, T12/T13, 2-way LDS merge) + T15 compute pipeline: S[t+1] MFMAs
// issue BEFORE softmax[t], so matrix-pipe latency hides under the serial
// softmax VALU chain within each wave. Two named S banks, 2x-unrolled loop.
// ---------------------------------------------------------------------------
#define ATTN_BODY(prev, nxt, t)                                              \
    {                                                                        \
        /* S[(t)+1] -> nxt (kc holds tile (t)+1) */                          \
        f32x16 zz_ = {};                                                     \
        __builtin_amdgcn_s_setprio(1);                                       \
        nxt = MFMA32(kc0, qf[0], zz_);                                       \
        nxt = MFMA32(kc1, qf[1], nxt);                                       \
        nxt = MFMA32(kc2, qf[2], nxt);                                       \
        nxt = MFMA32(kc3, qf[3], nxt);                                       \
        __builtin_amdgcn_s_setprio(0);                                       \
        /* reload kc <- tile (t)+2 (cover: softmax+PV below) */              \
        {                                                                    \
            const int nt2_ = (((t) + 2) & 31) * 2048;                        \
            kc0 = *(const s16x8*)(kp + nt2_);                                \
            kc1 = *(const s16x8*)(kp + nt2_ + 512);                          \
            kc2 = *(const s16x8*)(kp + nt2_ + 1024);                         \
            kc3 = *(const s16x8*)(kp + nt2_ + 1536);                         \
        }                                                                    \
        __builtin_amdgcn_sched_barrier(0);                                   \
        /* softmax on prev (tile t) — r9-proven idioms */                    \
        float pmax_ = tree_max(prev);                                        \
        pmax_ = fmaxf(pmax_, __shfl_xor(pmax_, 32));                         \
        if (!__all(pmax_ - m <= 8.0f)) {                                     \
            float mn_ = fmaxf(m, pmax_);                                     \
            float corr_ = exp2f(m - mn_);                                    \
            _Pragma("unroll")                                                \
            for (int i_ = 0; i_ < 16; i_++) { o0[i_] *= corr_; o1[i_] *= corr_; } \
            l *= corr_;                                                      \
            m = mn_;                                                         \
        }                                                                    \
        _Pragma("unroll")                                                    \
        for (int i_ = 0; i_ < 16; i_++) prev[i_] = exp2f(prev[i_] - m);      \
        float rs_ = tree_sum(prev);                                          \
        rs_ += __shfl_xor(rs_, 32);                                          \
        l += rs_;                                                            \
        PA pa_ = packP(prev);                                                \
        /* O += V^T * P  (vc holds tile t) */                                \
        __builtin_amdgcn_s_setprio(1);                                       \
        o0 = MFMA32(vc0, pa_.a, o0);                                         \
        o1 = MFMA32(vc1, pa_.a, o1);                                         \
        o0 = MFMA32(vc2, pa_.b, o0);                                         \
        o1 = MFMA32(vc3, pa_.b, o1);                                         \
        __builtin_amdgcn_s_setprio(0);                                       \
        /* reload vc <- tile (t)+1 (cover: next S + next softmax) */         \
        {                                                                    \
            const int nv_ = (((t) + 1) & 31) * 2048;                         \
            vc0 = *(const s16x8*)(vp + nv_);                                 \
            vc1 = *(const s16x8*)(vp + nv_ + 512);                           \
            vc2 = *(const s16x8*)(vp + nv_ + 1024);                          \
            vc3 = *(const s16x8*)(vp + nv_ + 1536);                          \
        }                                                                    \
    }

__global__ __launch_bounds__(256) void attn_kernel(
    const short* __restrict__ qbuf, const short* __restrict__ KP,
    const short* __restrict__ VP, short* __restrict__ aout)
{
    alignas(16) __shared__ float OL[2][64][32];   // [qsub][lane][reg]
    __shared__ float ML[2][2][64];                // [qsub][{m,l}][lane]

    const int bh = blockIdx.x, qt = blockIdx.y;
    const int tid = threadIdx.x, wave = tid >> 6, lane = tid & 63;
    const int qsub = wave >> 1, half = wave & 1;
    const int l31 = lane & 31, hi = lane >> 5;
    const int q0 = qt*64 + qsub*32;

    s16x8 qf[4];
    const short* qrow = qbuf + ((size_t)bh*SEQ + q0 + l31)*HD + 8*hi;
    #pragma unroll
    for (int ks = 0; ks < 4; ks++) qf[ks] = *(const s16x8*)(qrow + 16*ks);

    const short* kp = KP + ((size_t)bh*64 + half*32)*2048 + lane*8;
    const short* vp = VP + ((size_t)bh*64 + half*32)*2048 + lane*8;

    // prologue: kc <- tile 0
    s16x8 kc0 = *(const s16x8*)(kp);
    s16x8 kc1 = *(const s16x8*)(kp + 512);
    s16x8 kc2 = *(const s16x8*)(kp + 1024);
    s16x8 kc3 = *(const s16x8*)(kp + 1536);

    f32x16 o0 = {}, o1 = {};
    float m = -1e30f, l = 0.f;

    // S[0] -> sA
    f32x16 sA, sB;
    {
        f32x16 z = {};
        __builtin_amdgcn_s_setprio(1);
        sA = MFMA32(kc0, qf[0], z);
        sA = MFMA32(kc1, qf[1], sA);
        sA = MFMA32(kc2, qf[2], sA);
        sA = MFMA32(kc3, qf[3], sA);
        __builtin_amdgcn_s_setprio(0);
    }
    // kc <- tile 1; vc <- tile 0
    kc0 = *(const s16x8*)(kp + 2048);
    kc1 = *(const s16x8*)(kp + 2048 + 512);
    kc2 = *(const s16x8*)(kp + 2048 + 1024);
    kc3 = *(const s16x8*)(kp + 2048 + 1536);
    s16x8 vc0 = *(const s16x8*)(vp);
    s16x8 vc1 = *(const s16x8*)(vp + 512);
    s16x8 vc2 = *(const s16x8*)(vp + 1024);
    s16x8 vc3 = *(const s16x8*)(vp + 1536);

    #pragma unroll 1
    for (int it = 0; it < 32; it += 2) {
        ATTN_BODY(sA, sB, it)         // softmax+PV tile it;   S[it+1] -> sB
        ATTN_BODY(sB, sA, it + 1)     // softmax+PV tile it+1; S[it+2] -> sA
    }

    // ---- merge the two K-halves (r9 exact) ----
    if (half == 1) {
        float* ob = &OL[qsub][lane][0];
        #pragma unroll
        for (int i = 0; i < 8; i++) {
            const int slot = (i + (lane & 7)) & 7;
            f32x4 v;
            if (i < 4) { v[0]=o0[4*i]; v[1]=o0[4*i+1]; v[2]=o0[4*i+2]; v[3]=o0[4*i+3]; }
            else { const int j = i-4; v[0]=o1[4*j]; v[1]=o1[4*j+1]; v[2]=o1[4*j+2]; v[3]=o1[4*j+3]; }
            *(f32x4*)(ob + slot*4) = v;
        }
        ML[qsub][0][lane] = m;
        ML[qsub][1][lane] = l;
    }
    __syncthreads();
    if (half == 0) {
        const float m1 = ML[qsub][0][lane];
        const float l1 = ML[qsub][1][lane];
        const float ms = fmaxf(m, m1);
        const float c0 = exp2f(m - ms), c1 = exp2f(m1 - ms);
        const float inv = 1.0f / (l*c0 + l1*c1);
        const float* ob = &OL[qsub][lane][0];
        const int b = bh >> 4, h = bh & 15;
        short* dst = aout + ((size_t)(b*SEQ + q0 + l31))*DIM + h*HD;
        #pragma unroll
        for (int i = 0; i < 8; i++) {
            const int slot = (i + (lane & 7)) & 7;
            f32x4 p = *(const f32x4*)(ob + slot*4);
            s16x4 st;
            if (i < 4) {
                #pragma unroll
                for (int j = 0; j < 4; j++) st[j] = f2bf((o0[4*i+j]*c0 + p[j]*c1) * inv);
                *(s16x4*)(dst + 8*i + 4*hi) = st;
            } else {
                const int t3 = i - 4;
                #pragma unroll
                for (int j = 0; j < 4; j++) st[j] = f2bf((o1[4*t3+j]*c0 + p[j]*c1) * inv);
                *(s16x4*)(dst + 32 + 8*t3 + 4*hi) = st;
            }
        }
    }
}

// ---------------------------------------------------------------------------
extern "C" void kernel_launch(void* const* d_in, const int* in_sizes, int n_in,
                              void* d_out, int out_size, void* d_ws, size_t ws_size,
                              hipStream_t stream)
{
    const float* x     = (const float*)d_in[0];
    const float* Wqkv  = (const float*)d_in[1];
    const float* qg    = (const float*)d_in[2];
    const float* qbeta = (const float*)d_in[3];
    const float* kg    = (const float*)d_in[4];
    const float* kbeta = (const float*)d_in[5];
    const float* Wproj = (const float*)d_in[6];
    const float* bproj = (const float*)d_in[7];
    float* out = (float*)d_out;

    char* ws = (char*)d_ws;
    const size_t MB = 1024*1024;
    short* xb     = (short*)(ws);              // 8 MB; dead after gemm<0>
    short* KP     = (short*)(ws);              // reuses xb slot (written by repack)
    short* wqkvb  = (short*)(ws + 8*MB);       // 6 MB
    short* wprojb = (short*)(ws + 14*MB);      // 2 MB (live until gemm<1>)
    short* q      = (short*)(ws + 16*MB);      // 8 MB
    short* k      = (short*)(ws + 24*MB);      // 8 MB; dead after repack
    short* aout   = (short*)(ws + 24*MB);      // reuses k slot (written by attn)
    short* vrow   = (short*)(ws + 32*MB);      // 8 MB; dead after repack
    short* VP     = (short*)(ws + 40*MB);      // 8 MB

    // 1. fp32 -> bf16 conversions
    convert3<<<dim3(4096), 256, 0, stream>>>(x, Wqkv, Wproj, xb, wqkvb, wprojb);

    // 2. QKV GEMM + fused q/k LayerNorm, scatter
    gemm_bf16<0><<<dim3(3*DIM/128, ROWS/128), 256, 0, stream>>>(
        xb, wqkvb, nullptr, qg, qbeta, kg, kbeta, q, k, vrow, nullptr);

    // 3. Repack K,V into fragment order
    repack_kv<<<dim3(BATCH*HEADS, SEQ/64), 256, 0, stream>>>(k, vrow, KP, VP);

    // 4. Flash attention (q32/wave, 2-way split-K, T15 pipeline, bf16 out)
    attn_kernel<<<dim3(BATCH*HEADS, SEQ/64), 256, 0, stream>>>(q, KP, VP, aout);

    // 5. Projection GEMM + bias -> fp32 d_out
    gemm_bf16<1><<<dim3(DIM/128, ROWS/128), 256, 0, stream>>>(
        aout, wprojb, bproj, nullptr, nullptr, nullptr, nullptr,
        nullptr, nullptr, nullptr, out);
}

// Round 13
// 140.228 us; speedup vs baseline: 1.1850x; 1.0564x over previous
//
#include <hip/hip_runtime.h>

#define DIM 1024
#define HEADS 16
#define HD 64
#define BATCH 2
#define SEQ 2048
#define ROWS (BATCH*SEQ)          // 4096
#define EPS 1e-6f

typedef float f32x4  __attribute__((ext_vector_type(4)));
typedef float f32x16 __attribute__((ext_vector_type(16)));
typedef short s16x4  __attribute__((ext_vector_type(4)));
typedef short s16x8  __attribute__((ext_vector_type(8)));

static __device__ __forceinline__ short f2bf(float f) {
    union { float f; unsigned u; } x; x.f = f;
    unsigned r = x.u + 0x7FFFu + ((x.u >> 16) & 1u);
    return (short)(r >> 16);
}
static __device__ __forceinline__ s16x8 pack8(float4 lo, float4 hi) {
    s16x8 r;
    r[0]=f2bf(lo.x); r[1]=f2bf(lo.y); r[2]=f2bf(lo.z); r[3]=f2bf(lo.w);
    r[4]=f2bf(hi.x); r[5]=f2bf(hi.y); r[6]=f2bf(hi.z); r[7]=f2bf(hi.w);
    return r;
}
static __device__ __forceinline__ unsigned cvtpk(float a, float b) {
    unsigned r;
    asm("v_cvt_pk_bf16_f32 %0, %1, %2" : "=v"(r) : "v"(a), "v"(b));
    return r;
}
static __device__ __forceinline__ void gld16(short* l, const short* g) {
    __builtin_amdgcn_global_load_lds(
        (const __attribute__((address_space(1))) void*)g,
        (__attribute__((address_space(3))) void*)l, 16, 0, 0);
}

#define MFMA32(A,B,C) __builtin_amdgcn_mfma_f32_32x32x16_bf16(A, B, C, 0, 0, 0)
#define MFMA16(A,B,C) __builtin_amdgcn_mfma_f32_16x16x32_bf16(A, B, C, 0, 0, 0)

struct PA { s16x8 a, b; };
// P (lane's 32 keys for its q-col) -> two bf16 A-fragments (T12; proven r2-r12)
static __device__ __forceinline__ PA packP(const f32x16& s) {
    PA r;
    unsigned A0 = cvtpk(s[0], s[1]),  A1 = cvtpk(s[2], s[3]);
    unsigned B0 = cvtpk(s[4], s[5]),  B1 = cvtpk(s[6], s[7]);
    asm volatile("v_permlane32_swap_b32 %0, %1" : "+v"(A0), "+v"(B0));
    asm volatile("v_permlane32_swap_b32 %0, %1" : "+v"(A1), "+v"(B1));
    union { s16x8 v; unsigned u[4]; } w;
    w.u[0]=A0; w.u[1]=A1; w.u[2]=B0; w.u[3]=B1;
    r.a = w.v;
    unsigned C0 = cvtpk(s[8], s[9]),   C1 = cvtpk(s[10], s[11]);
    unsigned D0 = cvtpk(s[12], s[13]), D1 = cvtpk(s[14], s[15]);
    asm volatile("v_permlane32_swap_b32 %0, %1" : "+v"(C0), "+v"(D0));
    asm volatile("v_permlane32_swap_b32 %0, %1" : "+v"(C1), "+v"(D1));
    union { s16x8 v; unsigned u[4]; } w2;
    w2.u[0]=C0; w2.u[1]=C1; w2.u[2]=D0; w2.u[3]=D1;
    r.b = w2.v;
    return r;
}
static __device__ __forceinline__ float tree_max(const f32x16& s) {
    float t[8];
    #pragma unroll
    for (int i = 0; i < 8; i++) t[i] = fmaxf(s[i], s[i+8]);
    #pragma unroll
    for (int i = 0; i < 4; i++) t[i] = fmaxf(t[i], t[i+4]);
    return fmaxf(fmaxf(t[0], t[2]), fmaxf(t[1], t[3]));
}
static __device__ __forceinline__ float tree_sum(const f32x16& s) {
    float t[8];
    #pragma unroll
    for (int i = 0; i < 8; i++) t[i] = s[i] + s[i+8];
    #pragma unroll
    for (int i = 0; i < 4; i++) t[i] += t[i+4];
    return (t[0] + t[2]) + (t[1] + t[3]);
}

// ---------------------------------------------------------------------------
// fp32 -> bf16 conversion for x, W_qkv, W_proj (one pass, vectorized)
// ---------------------------------------------------------------------------
__global__ __launch_bounds__(256) void convert3(
    const float* __restrict__ x, const float* __restrict__ wq,
    const float* __restrict__ wp,
    short* __restrict__ xb, short* __restrict__ wqb, short* __restrict__ wpb)
{
    const int idx = blockIdx.x * 256 + threadIdx.x;   // one 8-elem chunk
    const int C1 = 4194304/8, C2 = 3145728/8;
    const float* src; short* dst; int off;
    if (idx < C1)            { src = x;  dst = xb;  off = idx; }
    else if (idx < C1 + C2)  { src = wq; dst = wqb; off = idx - C1; }
    else                     { src = wp; dst = wpb; off = idx - C1 - C2; }
    float4 a = ((const float4*)src)[off*2];
    float4 b = ((const float4*)src)[off*2 + 1];
    ((s16x8*)dst)[off] = pack8(a, b);
}

// ---------------------------------------------------------------------------
// bf16 GEMM, m97 structure: 128x128 tile, BK=64, global_load_lds staging.
// MODE 0: fused per-head LayerNorm on q/k; q written row-major [B,H,N,D];
//         K and V written DIRECTLY in MFMA-fragment order (KP/VP) —
//         repack kernel fused away. Mapping (inverse of old repack_kv):
//           KP[bh][key>>5][dim>>4][((dim&15)>>3)*32 + (key&31)][dim&7]
//           VP[bh][key>>5][2*((key&31)>>4)+(dim>>5)]
//             [((key&15)>>3)*32 + (dim&31)][key&7]
// MODE 1: bias add, fp32 out
// ---------------------------------------------------------------------------
#define BKG 64

template<int MODE>
__global__ __launch_bounds__(256) void gemm_bf16(
    const short* __restrict__ A, const short* __restrict__ W,
    const float* __restrict__ bias,
    const float* __restrict__ qg, const float* __restrict__ qbeta,
    const float* __restrict__ kg, const float* __restrict__ kbeta,
    short* __restrict__ qb, short* __restrict__ kpb, short* __restrict__ vpb,
    float* __restrict__ out)
{
    alignas(16) __shared__ short As[128*BKG];
    alignas(16) __shared__ short Bs[128*BKG];
    const int tid  = threadIdx.x;
    const int lane = tid & 63, wave = tid >> 6;
    const int wr = wave >> 1, wc = wave & 1;
    const int c = lane & 15, g = lane >> 4;
    const int brow = blockIdx.y * 128, bcol = blockIdx.x * 128;

    const int srow = lane >> 3;
    const int scol = (lane & 7) * 8;
    const short* ag = A + (size_t)(brow + srow)*DIM + scol;
    const short* wg = W + (size_t)(bcol + srow)*DIM + scol;

    f32x4 acc[4][4] = {};

    for (int k0 = 0; k0 < DIM; k0 += BKG) {
        #pragma unroll
        for (int j = 0; j < 4; j++) {
            const int rg = (wave*4 + j) * 8;
            gld16(&As[rg*BKG], ag + (size_t)rg*DIM + k0);
            gld16(&Bs[rg*BKG], wg + (size_t)rg*DIM + k0);
        }
        __syncthreads();

        #pragma unroll
        for (int ks = 0; ks < 2; ks++) {
            s16x8 af[4], bf[4];
            #pragma unroll
            for (int m = 0; m < 4; m++)
                af[m] = *(const s16x8*)&As[(wr*64 + m*16 + c)*BKG + ks*32 + g*8];
            #pragma unroll
            for (int n = 0; n < 4; n++)
                bf[n] = *(const s16x8*)&Bs[(wc*64 + n*16 + c)*BKG + ks*32 + g*8];
            #pragma unroll
            for (int m = 0; m < 4; m++)
                #pragma unroll
                for (int n = 0; n < 4; n++)
                    acc[m][n] = MFMA16(af[m], bf[n], acc[m][n]);
        }
        __syncthreads();
    }

    if (MODE == 0) {
        const int colbase = bcol + wc*64;
        const int t = colbase >> 10;               // 0:q 1:k 2:v
        const int h = (colbase >> 6) & 15;
        float gam[4], bet[4];
        float scale = 1.0f;
        if (t < 2) {
            const float* G  = (t == 0) ? qg : kg;
            const float* Bt = (t == 0) ? qbeta : kbeta;
            #pragma unroll
            for (int n = 0; n < 4; n++) { gam[n] = G[n*16 + c]; bet[n] = Bt[n*16 + c]; }
            if (t == 0) scale = 0.125f * 1.44269504088896340736f;  // D^-0.5 * log2e
        }
        #pragma unroll
        for (int m = 0; m < 4; m++) {
            #pragma unroll
            for (int j = 0; j < 4; j++) {
                const int row = brow + wr*64 + m*16 + g*4 + j;
                const int bi = row >> 11, ni = row & (SEQ-1);
                const int bh = bi*HEADS + h;
                float v0 = acc[m][0][j], v1 = acc[m][1][j];
                float v2 = acc[m][2][j], v3 = acc[m][3][j];
                if (t < 2) {
                    float s = (v0 + v1) + (v2 + v3);
                    s += __shfl_xor(s, 1); s += __shfl_xor(s, 2);
                    s += __shfl_xor(s, 4); s += __shfl_xor(s, 8);
                    const float mu = s * 0.015625f;
                    v0 -= mu; v1 -= mu; v2 -= mu; v3 -= mu;
                    float vv = (v0*v0 + v1*v1) + (v2*v2 + v3*v3);
                    vv += __shfl_xor(vv, 1); vv += __shfl_xor(vv, 2);
                    vv += __shfl_xor(vv, 4); vv += __shfl_xor(vv, 8);
                    const float rstd = rsqrtf(vv * 0.015625f + EPS);
                    v0 = (v0*rstd*gam[0] + bet[0]) * scale;
                    v1 = (v1*rstd*gam[1] + bet[1]) * scale;
                    v2 = (v2*rstd*gam[2] + bet[2]) * scale;
                    v3 = (v3*rstd*gam[3] + bet[3]) * scale;
                }
                if (t == 0) {
                    const size_t rb = ((size_t)bh*SEQ + ni)*HD;
                    qb[rb + 0*16 + c] = f2bf(v0);
                    qb[rb + 1*16 + c] = f2bf(v1);
                    qb[rb + 2*16 + c] = f2bf(v2);
                    qb[rb + 3*16 + c] = f2bf(v3);
                } else {
                    const size_t tb = ((size_t)bh*64 + (ni >> 5)) * 2048;
                    const int kl = ni & 31;
                    if (t == 1) {
                        // KP: dim = n*16+c -> + n*512, lane=(c>>3)*32+kl, e=c&7
                        const size_t b2 = tb + (size_t)(((c >> 3)*32 + kl)*8 + (c & 7));
                        kpb[b2 + 0*512] = f2bf(v0);
                        kpb[b2 + 1*512] = f2bf(v1);
                        kpb[b2 + 2*512] = f2bf(v2);
                        kpb[b2 + 3*512] = f2bf(v3);
                    } else {
                        // VP: sub=2*(kl>>4)+(n>>1), lane=((kl&15)>>3)*32+(n&1)*16+c, e=kl&7
                        const int hi2 = (kl & 15) >> 3, e2 = kl & 7;
                        const size_t b0 = tb + (size_t)((2*(kl >> 4))*512 + (hi2*32)*8 + e2);
                        vpb[b0 + (size_t)(c)*8]        = f2bf(v0);
                        vpb[b0 + (size_t)(16 + c)*8]   = f2bf(v1);
                        vpb[b0 + 512 + (size_t)(c)*8]      = f2bf(v2);
                        vpb[b0 + 512 + (size_t)(16 + c)*8] = f2bf(v3);
                    }
                }
            }
        }
    } else {
        #pragma unroll
        for (int n = 0; n < 4; n++) {
            const int col = bcol + wc*64 + n*16 + c;
            const float bv = bias[col];
            #pragma unroll
            for (int m = 0; m < 4; m++) {
                #pragma unroll
                for (int j = 0; j < 4; j++) {
                    const int row = brow + wr*64 + m*16 + g*4 + j;
                    out[(size_t)row*DIM + col] = acc[m][n][j] + bv;
                }
            }
        }
    }
}

// ---------------------------------------------------------------------------
// Flash attention: r9 exact structure (q32/wave, 2-way split-K, shfl_xor
// reduces, exp2f, T12/T13, register K/V pipeline, 2-way LDS merge) with
// __launch_bounds__(256, 4): cap total regs at 128/wave -> 4 waves/SIMD
// guaranteed residency (the register-file experiment).
// ---------------------------------------------------------------------------
__global__ __launch_bounds__(256, 4) void attn_kernel(
    const short* __restrict__ qbuf, const short* __restrict__ KP,
    const short* __restrict__ VP, short* __restrict__ aout)
{
    alignas(16) __shared__ float OL[2][64][32];   // [qsub][lane][reg]
    __shared__ float ML[2][2][64];                // [qsub][{m,l}][lane]

    const int bh = blockIdx.x, qt = blockIdx.y;
    const int tid = threadIdx.x, wave = tid >> 6, lane = tid & 63;
    const int qsub = wave >> 1, half = wave & 1;
    const int l31 = lane & 31, hi = lane >> 5;
    const int q0 = qt*64 + qsub*32;

    s16x8 qf[4];
    const short* qrow = qbuf + ((size_t)bh*SEQ + q0 + l31)*HD + 8*hi;
    #pragma unroll
    for (int ks = 0; ks < 4; ks++) qf[ks] = *(const s16x8*)(qrow + 16*ks);

    const short* kp = KP + ((size_t)bh*64 + half*32)*2048 + lane*8;
    const short* vp = VP + ((size_t)bh*64 + half*32)*2048 + lane*8;

    // prologue: tile 0 of this wave's K-half
    s16x8 kc0 = *(const s16x8*)(kp);
    s16x8 kc1 = *(const s16x8*)(kp + 512);
    s16x8 kc2 = *(const s16x8*)(kp + 1024);
    s16x8 kc3 = *(const s16x8*)(kp + 1536);
    s16x8 vc0 = *(const s16x8*)(vp);
    s16x8 vc1 = *(const s16x8*)(vp + 512);
    s16x8 vc2 = *(const s16x8*)(vp + 1024);
    s16x8 vc3 = *(const s16x8*)(vp + 1536);

    f32x16 o0 = {}, o1 = {};
    float m = -1e30f, l = 0.f;

    for (int it = 0; it < 32; it++) {
        // S^T = K*Q : lane holds 16 keys for q = q0+l31
        f32x16 s = {};
        __builtin_amdgcn_s_setprio(1);
        s = MFMA32(kc0, qf[0], s);
        s = MFMA32(kc1, qf[1], s);
        s = MFMA32(kc2, qf[2], s);
        s = MFMA32(kc3, qf[3], s);
        __builtin_amdgcn_s_setprio(0);

        // reload kc for next tile NOW (covered by softmax + PV below)
        const int nt = ((it + 1) & 31) * 2048;
        kc0 = *(const s16x8*)(kp + nt);
        kc1 = *(const s16x8*)(kp + nt + 512);
        kc2 = *(const s16x8*)(kp + nt + 1024);
        kc3 = *(const s16x8*)(kp + nt + 1536);
        __builtin_amdgcn_sched_barrier(0);

        // softmax (r9 exact)
        float pmax = tree_max(s);
        pmax = fmaxf(pmax, __shfl_xor(pmax, 32));

        if (!__all(pmax - m <= 8.0f)) {           // defer-max (T13)
            float mn = fmaxf(m, pmax);
            float corr = exp2f(m - mn);
            #pragma unroll
            for (int i = 0; i < 16; i++) { o0[i] *= corr; o1[i] *= corr; }
            l *= corr;
            m = mn;
        }
        #pragma unroll
        for (int i = 0; i < 16; i++) s[i] = exp2f(s[i] - m);
        float rs = tree_sum(s);
        rs += __shfl_xor(rs, 32);
        l += rs;

        // P -> bf16 A-fragments (T12)
        PA pa = packP(s);

        // O^T += V^T * P
        __builtin_amdgcn_s_setprio(1);
        o0 = MFMA32(vc0, pa.a, o0);
        o1 = MFMA32(vc1, pa.a, o1);
        o0 = MFMA32(vc2, pa.b, o0);
        o1 = MFMA32(vc3, pa.b, o1);
        __builtin_amdgcn_s_setprio(0);

        // reload vc for next tile (covered by next iter's S phase + softmax)
        vc0 = *(const s16x8*)(vp + nt);
        vc1 = *(const s16x8*)(vp + nt + 512);
        vc2 = *(const s16x8*)(vp + nt + 1024);
        vc3 = *(const s16x8*)(vp + nt + 1536);
    }

    // ---- merge the two K-halves (r9 exact) ----
    if (half == 1) {
        float* ob = &OL[qsub][lane][0];
        #pragma unroll
        for (int i = 0; i < 8; i++) {
            const int slot = (i + (lane & 7)) & 7;
            f32x4 v;
            if (i < 4) { v[0]=o0[4*i]; v[1]=o0[4*i+1]; v[2]=o0[4*i+2]; v[3]=o0[4*i+3]; }
            else { const int j = i-4; v[0]=o1[4*j]; v[1]=o1[4*j+1]; v[2]=o1[4*j+2]; v[3]=o1[4*j+3]; }
            *(f32x4*)(ob + slot*4) = v;
        }
        ML[qsub][0][lane] = m;
        ML[qsub][1][lane] = l;
    }
    __syncthreads();
    if (half == 0) {
        const float m1 = ML[qsub][0][lane];
        const float l1 = ML[qsub][1][lane];
        const float ms = fmaxf(m, m1);
        const float c0 = exp2f(m - ms), c1 = exp2f(m1 - ms);
        const float inv = 1.0f / (l*c0 + l1*c1);
        const float* ob = &OL[qsub][lane][0];
        const int b = bh >> 4, h = bh & 15;
        short* dst = aout + ((size_t)(b*SEQ + q0 + l31))*DIM + h*HD;
        #pragma unroll
        for (int i = 0; i < 8; i++) {
            const int slot = (i + (lane & 7)) & 7;
            f32x4 p = *(const f32x4*)(ob + slot*4);
            s16x4 st;
            if (i < 4) {
                #pragma unroll
                for (int j = 0; j < 4; j++) st[j] = f2bf((o0[4*i+j]*c0 + p[j]*c1) * inv);
                *(s16x4*)(dst + 8*i + 4*hi) = st;
            } else {
                const int t3 = i - 4;
                #pragma unroll
                for (int j = 0; j < 4; j++) st[j] = f2bf((o1[4*t3+j]*c0 + p[j]*c1) * inv);
                *(s16x4*)(dst + 32 + 8*t3 + 4*hi) = st;
            }
        }
    }
}

// ---------------------------------------------------------------------------
extern "C" void kernel_launch(void* const* d_in, const int* in_sizes, int n_in,
                              void* d_out, int out_size, void* d_ws, size_t ws_size,
                              hipStream_t stream)
{
    const float* x     = (const float*)d_in[0];
    const float* Wqkv  = (const float*)d_in[1];
    const float* qg    = (const float*)d_in[2];
    const float* qbeta = (const float*)d_in[3];
    const float* kg    = (const float*)d_in[4];
    const float* kbeta = (const float*)d_in[5];
    const float* Wproj = (const float*)d_in[6];
    const float* bproj = (const float*)d_in[7];
    float* out = (float*)d_out;

    char* ws = (char*)d_ws;
    const size_t MB = 1024*1024;
    short* xb     = (short*)(ws);              // 8 MB; dead after gemm<0>
    short* aout   = (short*)(ws);              // reuses xb slot (written by attn)
    short* wqkvb  = (short*)(ws + 8*MB);       // 6 MB
    short* wprojb = (short*)(ws + 14*MB);      // 2 MB (live until gemm<1>)
    short* q      = (short*)(ws + 16*MB);      // 8 MB
    short* KP     = (short*)(ws + 24*MB);      // 8 MB (fragment-order K)
    short* VP     = (short*)(ws + 32*MB);      // 8 MB (fragment-order V)

    // 1. fp32 -> bf16 conversions
    convert3<<<dim3(4096), 256, 0, stream>>>(x, Wqkv, Wproj, xb, wqkvb, wprojb);

    // 2. QKV GEMM + fused q/k LayerNorm + fused K/V fragment repack
    gemm_bf16<0><<<dim3(3*DIM/128, ROWS/128), 256, 0, stream>>>(
        xb, wqkvb, nullptr, qg, qbeta, kg, kbeta, q, KP, VP, nullptr);

    // 3. Flash attention (q32/wave, 2-way split-K, launch_bounds(256,4))
    attn_kernel<<<dim3(BATCH*HEADS, SEQ/64), 256, 0, stream>>>(q, KP, VP, aout);

    // 4. Projection GEMM + bias -> fp32 d_out
    gemm_bf16<1><<<dim3(DIM/128, ROWS/128), 256, 0, stream>>>(
        aout, wprojb, bproj, nullptr, nullptr, nullptr, nullptr,
        nullptr, nullptr, nullptr, out);
}